// Round 7
// baseline (531.969 us; speedup 1.0000x reference)
//
#include <hip/hip_runtime.h>

#define BB 256
#define TT 2048
#define II 128
#define HH 128
#define GS 16              // steps per group
#define NG (TT / GS)       // 128 groups
#define HREP (HH + 8)      // replicated-hA padded stride (136 shorts)

typedef __attribute__((ext_vector_type(8))) short short8;  // 8 bf16 (4 VGPR)
typedef __attribute__((ext_vector_type(4))) float f32x4;   // MFMA C/D

// Light per-step barrier: drain LDS ops then barrier in ONE asm block
// (vmcnt NOT drained — x-prefetch loads / out-stores fly across steps).
__device__ __forceinline__ void step_barrier() {
    asm volatile("s_waitcnt lgkmcnt(0)\n\ts_barrier" ::: "memory");
}

__device__ __forceinline__ float tanh_fast(float s) {
    // tanh(s) = 1 - 2/(e^{2s}+1); e^{2s} = 2^(s * 2/ln2), one v_exp_f32.
#if __has_builtin(__builtin_amdgcn_exp2f)
    const float e = __builtin_amdgcn_exp2f(s * 2.8853900817779268f);
#else
    const float e = exp2f(s * 2.8853900817779268f);
#endif
    return 1.0f - 2.0f * __builtin_amdgcn_rcpf(e + 1.0f);
}

// float -> bf16 round-to-nearest-even (scalar/setup paths)
__device__ __forceinline__ unsigned int f2bf(float f) {
    unsigned int u = __float_as_uint(f);
    u += 0x7FFF + ((u >> 16) & 1);
    return u >> 16;
}
// hot-path pack: ONE v_cvt_pk_bf16_f32 (lo = a, hi = b)
__device__ __forceinline__ unsigned int cvtpk(float a, float b) {
    unsigned int r;
    asm("v_cvt_pk_bf16_f32 %0, %1, %2" : "=v"(r) : "v"(a), "v"(b));
    return r;
}

// R20 = R19 with the x-wave out-store addressing bug fixed (R19's rolling
// pointer was off by one slot and ran past the batch row -> memory fault;
// reverted to R18's proven absolute xout[(T-1)*HH], which runs on PARKED
// x-waves, off the critical path). R19's two real changes retained:
//  (1) REPLICATED hA: hAr[4][2][HH+8] — one copy per 16-lane row-group.
//      All 64 lanes ds_write_b32 unconditionally (no lane<16 exec-mask on
//      the critical tail). Stride 136 shorts: write aliasing across row-
//      groups is exactly 2-way (free, m136); b128 broadcast reads start at
//      banks {0,12,24,4} per group — disjoint quads, conflict-free.
//      Replicas hold identical data (rows are broadcast-redundant).
//  (2) axbuf 3 -> 2 buffers, distance-1: window at group g (w==14) writes
//      axbuf[(g+1)&1] (ax of group g+1, from xstage[g&1] = x(g+1)); h's
//      w==15 prefetch reads it one barrier later. Buffer (g+1)&1 is dead
//      from group g w==0 (last read: group g-1's w==14 prefetch of wn=15)
//      — race-free. Simpler index math, simpler prologue.
// Everything else R18 verbatim: parked x-waves (out-streaming + single
// w==14 window), persistent ax-seeded d00/d10, z4-fed e-accs, broadcast-A
// ds_reads, permuted hA k-layout matched by the WH gather, setprio(1) on
// h-waves, fire-and-forget stores, lgkm-only step barrier.
__launch_bounds__(512, 1)
__global__ void rnn_pipe(const float* __restrict__ x,
                         const float* __restrict__ w_ih,
                         const float* __restrict__ w_hh,
                         const float* __restrict__ b_ih,
                         const float* __restrict__ b_hh,
                         float* __restrict__ out) {
    const int b    = blockIdx.x;
    const int tid  = threadIdx.x;
    const int wave = tid >> 6;
    const int lane = tid & 63;
    const bool hw  = (wave < 4);

    __shared__ __align__(16) unsigned short hAr[4][2][HREP];     // replicated bf16 h ping-pong
    __shared__ __align__(16) float axbuf[2][GS][HH];             // 16 KB, distance-1 pipeline
    __shared__ __align__(16) unsigned short xstage[2][4][64][8]; // 8 KB bf16 A-frags

    const float* xb = x + (size_t)b * (TT * II);
    const f32x4 z4 = {0.f, 0.f, 0.f, 0.f};   // hoisted MFMA C zero

    // ---------------- h-wave setup: W_hh B-frags (bf16, k-permuted) ----------------
    const int jb_h = (wave & 3) * 32;    // h-wave owns cols [jb_h, jb_h+32)
    short8 WH[2][4];
    if (hw) {
#pragma unroll
        for (int nt = 0; nt < 2; ++nt) {
            const int jj = jb_h + nt * 16 + (lane & 15);
#pragma unroll
            for (int kf = 0; kf < 4; ++kf) {
                short8 s;
#pragma unroll
                for (int e = 0; e < 8; ++e) {
                    const int kp = kf * 32 + (lane >> 4) * 8 + e;  // A-slot index
                    const int mm = kp & 31;
                    // slot -> original k: 32a+2c -> 32a+c ; 32a+2c+1 -> 32a+16+c
                    const int ko = (kp & ~31) + (mm >> 1) + ((mm & 1) << 4);
                    s[e] = (short)f2bf(w_hh[(size_t)jj * HH + ko]);
                }
                WH[nt][kf] = s;
            }
        }
    }

    // ---------------- x-wave setup ----------------
    const int xwq = wave - 4;        // 0..3
    const int jb  = xwq * 32;        // owns j in [jb, jb+32): 2 N-tiles
    short8 WF[2][4];
    float biasv[2];
    f32x4 bs0 = z4, bs1 = z4;        // bias splats (MFMA C seeds)
    const int q   = tid - 256;       // 0..255 for x-threads
    const int t_s = q >> 4;          // 0..15
    const int m   = q & 15;
    const int i0  = m * 8;
    const int kfs = m >> 2;                  // k-frag of this chunk
    const int lps = (m & 3) * 16 + t_s;      // A-frag lane slot
    const int c16 = lane & 15;
    const int rg  = lane >> 4;               // row-group 0..3
    if (!hw) {
#pragma unroll
        for (int nt = 0; nt < 2; ++nt) {
            const int jj = jb + nt * 16 + (lane & 15);
            biasv[nt] = b_ih[jj] + b_hh[jj];
#pragma unroll
            for (int kf = 0; kf < 4; ++kf) {
                const float* wp = w_ih + (size_t)jj * II + kf * 32 + (lane >> 4) * 8;
                short8 s;
#pragma unroll
                for (int e = 0; e < 8; ++e) s[e] = (short)f2bf(wp[e]);
                WF[nt][kf] = s;
            }
        }
#pragma unroll
        for (int r = 0; r < 4; ++r) { bs0[r] = biasv[0]; bs1[r] = biasv[1]; }
    }

#define STAGE_X(BUF, R0, R1) do { \
        uint4 P_; \
        P_.x = cvtpk((R0).x, (R0).y); P_.y = cvtpk((R0).z, (R0).w); \
        P_.z = cvtpk((R1).x, (R1).y); P_.w = cvtpk((R1).z, (R1).w); \
        *reinterpret_cast<uint4*>(&xstage[BUF][kfs][lps][0]) = P_; } while (0)

// chained XPROJ — used in the prologue only (not perf-critical)
#define XPROJ(SB, AB) do { \
        const short8 PA0 = *reinterpret_cast<const short8*>(&xstage[SB][0][lane][0]); \
        const short8 PA1 = *reinterpret_cast<const short8*>(&xstage[SB][1][lane][0]); \
        const short8 PA2 = *reinterpret_cast<const short8*>(&xstage[SB][2][lane][0]); \
        const short8 PA3 = *reinterpret_cast<const short8*>(&xstage[SB][3][lane][0]); \
        f32x4 ac0 = z4, ac1 = z4; \
        ac0 = __builtin_amdgcn_mfma_f32_16x16x32_bf16(PA0, WF[0][0], ac0, 0, 0, 0); \
        ac0 = __builtin_amdgcn_mfma_f32_16x16x32_bf16(PA1, WF[0][1], ac0, 0, 0, 0); \
        ac0 = __builtin_amdgcn_mfma_f32_16x16x32_bf16(PA2, WF[0][2], ac0, 0, 0, 0); \
        ac0 = __builtin_amdgcn_mfma_f32_16x16x32_bf16(PA3, WF[0][3], ac0, 0, 0, 0); \
        ac1 = __builtin_amdgcn_mfma_f32_16x16x32_bf16(PA0, WF[1][0], ac1, 0, 0, 0); \
        ac1 = __builtin_amdgcn_mfma_f32_16x16x32_bf16(PA1, WF[1][1], ac1, 0, 0, 0); \
        ac1 = __builtin_amdgcn_mfma_f32_16x16x32_bf16(PA2, WF[1][2], ac1, 0, 0, 0); \
        ac1 = __builtin_amdgcn_mfma_f32_16x16x32_bf16(PA3, WF[1][3], ac1, 0, 0, 0); \
        const int c_ = lane & 15, rb_ = (lane >> 4) * 4; \
        _Pragma("unroll") \
        for (int r = 0; r < 4; ++r) { \
            axbuf[AB][rb_ + r][jb + c_]      = ac0[r] + biasv[0]; \
            axbuf[AB][rb_ + r][jb + 16 + c_] = ac1[r] + biasv[1]; \
        } } while (0)

    // -------- prologue: axbuf[0]<-ax(g0); xstage[0]<-x(g1); nr<-x(g2) --------
    float4 nr0, nr1;
    if (!hw) {
        float4 p0 = *reinterpret_cast<const float4*>(&xb[t_s * II + i0]);
        float4 p1 = *reinterpret_cast<const float4*>(&xb[t_s * II + i0 + 4]);
        STAGE_X(1, p0, p1);                    // xstage[1] <- x of group 0 (temp)
    }
    for (int i = tid; i < 4 * 2 * HREP; i += 512)
        ((unsigned short*)hAr)[i] = 0;         // bf16 zero (permutation-invariant)
    __syncthreads();
    if (!hw) {
        XPROJ(1, 0);                           // axbuf[0] <- ax(group 0)
        float4 p0 = *reinterpret_cast<const float4*>(&xb[(GS + t_s) * II + i0]);
        float4 p1 = *reinterpret_cast<const float4*>(&xb[(GS + t_s) * II + i0 + 4]);
        STAGE_X(0, p0, p1);                    // xstage[0] <- x of group 1
        nr0 = *reinterpret_cast<const float4*>(&xb[(size_t)(2 * GS + t_s) * II + i0]);
        nr1 = *reinterpret_cast<const float4*>(&xb[(size_t)(2 * GS + t_s) * II + i0 + 4]);
    }
    __syncthreads();

    // h-wave persistent state
    float axn0 = 0.f, axn1 = 0.f;
    f32x4 d00 = z4, d10 = z4;      // persistent ax-seeded accumulators
    if (hw) {
        axn0 = axbuf[0][0][jb_h + c16];
        axn1 = axbuf[0][0][jb_h + 16 + c16];
        __builtin_amdgcn_s_setprio(1);    // protect the serial chain's MFMAs
    }

    // x-wave out-store base: lane c<16 -> col jb+c; lane 16+c -> col jb+16+c
    float* xout = nullptr;
    if (!hw && lane < 32) {
        xout = out + (size_t)b * (TT * HH) + jb + c16 + ((lane & 16) ? 16 : 0);
    }

    // ---------------- main loop ----------------
    for (int g = 0; g < NG; ++g) {
#pragma unroll
        for (int w = 0; w < GS; ++w) {
            if (hw) {
                const int p  = w & 1;
                const int ko = rg * 8;
                // A = h broadcast into all 16 rows; each row-group reads its
                // own replica (conflict-free by HREP stride choice)
                const short8 A0 = *reinterpret_cast<const short8*>(&hAr[rg][p][ 0 + ko]);
                const short8 A1 = *reinterpret_cast<const short8*>(&hAr[rg][p][32 + ko]);
                const short8 A2 = *reinterpret_cast<const short8*>(&hAr[rg][p][64 + ko]);
                const short8 A3 = *reinterpret_cast<const short8*>(&hAr[rg][p][96 + ko]);
                // seed ax into C of the first acc of each n-tile (1 mov each;
                // stale [1..3] never read, bounded accumulation)
                d00[0] = axn0;
                d10[0] = axn1;
                f32x4 e01, e02, e03, e11, e12, e13;
                d00 = __builtin_amdgcn_mfma_f32_16x16x32_bf16(A0, WH[0][0], d00, 0, 0, 0);
                e01 = __builtin_amdgcn_mfma_f32_16x16x32_bf16(A1, WH[0][1], z4,  0, 0, 0);
                e02 = __builtin_amdgcn_mfma_f32_16x16x32_bf16(A2, WH[0][2], z4,  0, 0, 0);
                e03 = __builtin_amdgcn_mfma_f32_16x16x32_bf16(A3, WH[0][3], z4,  0, 0, 0);
                d10 = __builtin_amdgcn_mfma_f32_16x16x32_bf16(A0, WH[1][0], d10, 0, 0, 0);
                e11 = __builtin_amdgcn_mfma_f32_16x16x32_bf16(A1, WH[1][1], z4,  0, 0, 0);
                e12 = __builtin_amdgcn_mfma_f32_16x16x32_bf16(A2, WH[1][2], z4,  0, 0, 0);
                e13 = __builtin_amdgcn_mfma_f32_16x16x32_bf16(A3, WH[1][3], z4,  0, 0, 0);
                // prefetch next step's ax (hidden under MFMA completion).
                // w==15 reads next group's buffer — written at w==14, one
                // barrier earlier (distance-1 pipeline) — race-free.
                {
                    const int wn  = (w + 1) & (GS - 1);
                    const int gnb = (w == GS - 1) ? ((g + 1) & 1) : (g & 1);
                    axn0 = axbuf[gnb][wn][jb_h + c16];
                    axn1 = axbuf[gnb][wn][jb_h + 16 + c16];
                }
                // 2-level add tree (ax already inside d00/d10)
                const float s0 = (d00[0] + e01[0]) + (e02[0] + e03[0]);
                const float s1 = (d10[0] + e11[0]) + (e12[0] + e13[0]);
                const float hn0 = tanh_fast(s0);
                const float hn1 = tanh_fast(s1);
                const unsigned int hpk = cvtpk(hn0, hn1);
                // permuted layout: cols (jb_h+c, jb_h+16+c) adjacent -> ONE
                // packed dword write; ALL lanes write (own replica, no mask)
                *reinterpret_cast<unsigned int*>(&hAr[rg][p ^ 1][jb_h + 2 * c16]) = hpk;
            } else {
                // ---- park-and-store: stream out[T-1] from hAr[0] while h computes T ----
                const int T = (g << 4) + w;
                if (T != 0 && lane < 32) {
                    const unsigned int rd = *reinterpret_cast<const unsigned int*>(
                        &hAr[0][w & 1][jb + 2 * c16]);
                    const unsigned int v = (lane & 16) ? (rd & 0xffff0000u) : (rd << 16);
                    xout[(size_t)(T - 1) * HH] = __uint_as_float(v);
                }
                if (w == 14) {
                    // ---- the ENTIRE per-group x pipeline, one window ----
                    if (g + 1 < NG) {
                        // project ax for group g+1 from xstage[g&1] (= x(g+1))
                        const short8 XA0 = *reinterpret_cast<const short8*>(&xstage[g & 1][0][lane][0]);
                        const short8 XA1 = *reinterpret_cast<const short8*>(&xstage[g & 1][1][lane][0]);
                        const short8 XA2 = *reinterpret_cast<const short8*>(&xstage[g & 1][2][lane][0]);
                        const short8 XA3 = *reinterpret_cast<const short8*>(&xstage[g & 1][3][lane][0]);
                        // 8 independent MFMAs (bias-seeded first pair) + 2-level tree
                        f32x4 xp0, xp1, xp2, xp3, yp0, yp1, yp2, yp3;
                        xp0 = __builtin_amdgcn_mfma_f32_16x16x32_bf16(XA0, WF[0][0], bs0, 0, 0, 0);
                        yp0 = __builtin_amdgcn_mfma_f32_16x16x32_bf16(XA0, WF[1][0], bs1, 0, 0, 0);
                        xp1 = __builtin_amdgcn_mfma_f32_16x16x32_bf16(XA1, WF[0][1], z4, 0, 0, 0);
                        yp1 = __builtin_amdgcn_mfma_f32_16x16x32_bf16(XA1, WF[1][1], z4, 0, 0, 0);
                        xp2 = __builtin_amdgcn_mfma_f32_16x16x32_bf16(XA2, WF[0][2], z4, 0, 0, 0);
                        yp2 = __builtin_amdgcn_mfma_f32_16x16x32_bf16(XA2, WF[1][2], z4, 0, 0, 0);
                        xp3 = __builtin_amdgcn_mfma_f32_16x16x32_bf16(XA3, WF[0][3], z4, 0, 0, 0);
                        yp3 = __builtin_amdgcn_mfma_f32_16x16x32_bf16(XA3, WF[1][3], z4, 0, 0, 0);
                        const f32x4 t0 = (xp0 + xp1) + (xp2 + xp3);
                        const f32x4 t1 = (yp0 + yp1) + (yp2 + yp3);
                        const int c_ = lane & 15, rb_ = (lane >> 4) * 4;
#pragma unroll
                        for (int r = 0; r < 4; ++r) {
                            axbuf[(g + 1) & 1][rb_ + r][jb + c_]      = t0[r];
                            axbuf[(g + 1) & 1][rb_ + r][jb + 16 + c_] = t1[r];
                        }
                    }
                    if (g + 2 < NG) {
                        STAGE_X((g + 1) & 1, nr0, nr1);   // xstage[(g+1)&1] <- x(g+2)
                    }
                    if (g + 3 < NG) {
                        const int tb = (g + 3) * GS;      // load x(g+3) for next window
                        nr0 = *reinterpret_cast<const float4*>(&xb[(size_t)(tb + t_s) * II + i0]);
                        nr1 = *reinterpret_cast<const float4*>(&xb[(size_t)(tb + t_s) * II + i0 + 4]);
                    }
                }
            }
            step_barrier();
        }
    }

    // ---------------- epilogue: flush out[TT-1] (in hAr[0][0] after last step) ----------------
    if (!hw && lane < 32) {
        const unsigned int rd = *reinterpret_cast<const unsigned int*>(
            &hAr[0][0][jb + 2 * c16]);
        const unsigned int v = (lane & 16) ? (rd & 0xffff0000u) : (rd << 16);
        xout[(size_t)(TT - 1) * HH] = __uint_as_float(v);
    }
#undef XPROJ
#undef STAGE_X
}

extern "C" void kernel_launch(void* const* d_in, const int* in_sizes, int n_in,
                              void* d_out, int out_size, void* d_ws, size_t ws_size,
                              hipStream_t stream) {
    const float* x    = (const float*)d_in[0];
    const float* w_ih = (const float*)d_in[1];
    const float* w_hh = (const float*)d_in[2];
    const float* b_ih = (const float*)d_in[3];
    const float* b_hh = (const float*)d_in[4];
    float* out = (float*)d_out;

    rnn_pipe<<<BB, 512, 0, stream>>>(x, w_ih, w_hh, b_ih, b_hh, out);
}

// Round 8
// 464.711 us; speedup vs baseline: 1.1447x; 1.1447x over previous
//
#include <hip/hip_runtime.h>

#define BB 256
#define TT 2048
#define II 128
#define HH 128
#define GS 16              // steps per group
#define NG (TT / GS)       // 128 groups

typedef __attribute__((ext_vector_type(8))) short short8;  // 8 bf16 (4 VGPR)
typedef __attribute__((ext_vector_type(4))) float f32x4;   // MFMA C/D

// Light per-step barrier: drain LDS ops then barrier in ONE asm block
// (vmcnt NOT drained — x-prefetch loads / out-stores fly across steps).
__device__ __forceinline__ void step_barrier() {
    asm volatile("s_waitcnt lgkmcnt(0)\n\ts_barrier" ::: "memory");
}

__device__ __forceinline__ float tanh_fast(float s) {
    // tanh(s) = 1 - 2/(e^{2s}+1); e^{2s} = 2^(s * 2/ln2), one v_exp_f32.
#if __has_builtin(__builtin_amdgcn_exp2f)
    const float e = __builtin_amdgcn_exp2f(s * 2.8853900817779268f);
#else
    const float e = exp2f(s * 2.8853900817779268f);
#endif
    return 1.0f - 2.0f * __builtin_amdgcn_rcpf(e + 1.0f);
}

// float -> bf16 round-to-nearest-even (scalar/setup paths)
__device__ __forceinline__ unsigned int f2bf(float f) {
    unsigned int u = __float_as_uint(f);
    u += 0x7FFF + ((u >> 16) & 1);
    return u >> 16;
}
// hot-path pack: ONE v_cvt_pk_bf16_f32 (lo = a, hi = b)
__device__ __forceinline__ unsigned int cvtpk(float a, float b) {
    unsigned int r;
    asm("v_cvt_pk_bf16_f32 %0, %1, %2" : "=v"(r) : "v"(a), "v"(b));
    return r;
}

// R21 = R18 verbatim (the session's best: 465.7 µs). R19 (rolling-pointer
// OOB crash) and R20 (replicated hA: +4.2M bank-conflict cycles, MfmaUtil
// 24.5->21.3, +77 c/step) both refuted their hypotheses; the exec-mask and
// buffer-index micro-costs they targeted were never on the critical path.
// R18 structure: 4 h-waves (serial chain: broadcast-A ds_reads -> 8
// independent-accumulator MFMAs -> 2-level tree -> tanh -> single packed
// ds_write_b32 into permuted hA) + 4 parked x-waves (out-streaming every
// step + the ENTIRE per-group x pipeline in one w==14 window; distance-2
// ax pipeline across 3 buffers), lgkm-only step barrier, setprio(1) on
// h-waves, fire-and-forget global stores.
__launch_bounds__(512, 1)
__global__ void rnn_pipe(const float* __restrict__ x,
                         const float* __restrict__ w_ih,
                         const float* __restrict__ w_hh,
                         const float* __restrict__ b_ih,
                         const float* __restrict__ b_hh,
                         float* __restrict__ out) {
    const int b    = blockIdx.x;
    const int tid  = threadIdx.x;
    const int wave = tid >> 6;
    const int lane = tid & 63;
    const bool hw  = (wave < 4);

    __shared__ __align__(16) unsigned short hA[2][HH];           // bf16 h ping-pong (k-permuted)
    __shared__ __align__(16) float axbuf[3][GS][HH];             // 24 KB, distance-2 pipeline
    __shared__ __align__(16) unsigned short xstage[2][4][64][8]; // 8 KB bf16 A-frags

    const float* xb = x + (size_t)b * (TT * II);
    const f32x4 z4 = {0.f, 0.f, 0.f, 0.f};   // hoisted MFMA C zero

    // ---------------- h-wave setup: W_hh B-frags (bf16, k-permuted) ----------------
    const int jb_h = (wave & 3) * 32;    // h-wave owns cols [jb_h, jb_h+32)
    short8 WH[2][4];
    if (hw) {
#pragma unroll
        for (int nt = 0; nt < 2; ++nt) {
            const int jj = jb_h + nt * 16 + (lane & 15);
#pragma unroll
            for (int kf = 0; kf < 4; ++kf) {
                short8 s;
#pragma unroll
                for (int e = 0; e < 8; ++e) {
                    const int kp = kf * 32 + (lane >> 4) * 8 + e;  // A-slot index
                    const int mm = kp & 31;
                    // slot -> original k: 32a+2c -> 32a+c ; 32a+2c+1 -> 32a+16+c
                    const int ko = (kp & ~31) + (mm >> 1) + ((mm & 1) << 4);
                    s[e] = (short)f2bf(w_hh[(size_t)jj * HH + ko]);
                }
                WH[nt][kf] = s;
            }
        }
    }

    // ---------------- x-wave setup ----------------
    const int xwq = wave - 4;        // 0..3
    const int jb  = xwq * 32;        // owns j in [jb, jb+32): 2 N-tiles
    short8 WF[2][4];
    float biasv[2];
    f32x4 bs0 = z4, bs1 = z4;        // bias splats (MFMA C seeds)
    const int q   = tid - 256;       // 0..255 for x-threads
    const int t_s = q >> 4;          // 0..15
    const int m   = q & 15;
    const int i0  = m * 8;
    const int kfs = m >> 2;                  // k-frag of this chunk
    const int lps = (m & 3) * 16 + t_s;      // A-frag lane slot
    const int c16 = lane & 15;
    if (!hw) {
#pragma unroll
        for (int nt = 0; nt < 2; ++nt) {
            const int jj = jb + nt * 16 + (lane & 15);
            biasv[nt] = b_ih[jj] + b_hh[jj];
#pragma unroll
            for (int kf = 0; kf < 4; ++kf) {
                const float* wp = w_ih + (size_t)jj * II + kf * 32 + (lane >> 4) * 8;
                short8 s;
#pragma unroll
                for (int e = 0; e < 8; ++e) s[e] = (short)f2bf(wp[e]);
                WF[nt][kf] = s;
            }
        }
#pragma unroll
        for (int r = 0; r < 4; ++r) { bs0[r] = biasv[0]; bs1[r] = biasv[1]; }
    }

#define STAGE_X(BUF, R0, R1) do { \
        uint4 P_; \
        P_.x = cvtpk((R0).x, (R0).y); P_.y = cvtpk((R0).z, (R0).w); \
        P_.z = cvtpk((R1).x, (R1).y); P_.w = cvtpk((R1).z, (R1).w); \
        *reinterpret_cast<uint4*>(&xstage[BUF][kfs][lps][0]) = P_; } while (0)

// chained XPROJ — used in the prologue only (not perf-critical)
#define XPROJ(SB, AB) do { \
        const short8 PA0 = *reinterpret_cast<const short8*>(&xstage[SB][0][lane][0]); \
        const short8 PA1 = *reinterpret_cast<const short8*>(&xstage[SB][1][lane][0]); \
        const short8 PA2 = *reinterpret_cast<const short8*>(&xstage[SB][2][lane][0]); \
        const short8 PA3 = *reinterpret_cast<const short8*>(&xstage[SB][3][lane][0]); \
        f32x4 ac0 = z4, ac1 = z4; \
        ac0 = __builtin_amdgcn_mfma_f32_16x16x32_bf16(PA0, WF[0][0], ac0, 0, 0, 0); \
        ac0 = __builtin_amdgcn_mfma_f32_16x16x32_bf16(PA1, WF[0][1], ac0, 0, 0, 0); \
        ac0 = __builtin_amdgcn_mfma_f32_16x16x32_bf16(PA2, WF[0][2], ac0, 0, 0, 0); \
        ac0 = __builtin_amdgcn_mfma_f32_16x16x32_bf16(PA3, WF[0][3], ac0, 0, 0, 0); \
        ac1 = __builtin_amdgcn_mfma_f32_16x16x32_bf16(PA0, WF[1][0], ac1, 0, 0, 0); \
        ac1 = __builtin_amdgcn_mfma_f32_16x16x32_bf16(PA1, WF[1][1], ac1, 0, 0, 0); \
        ac1 = __builtin_amdgcn_mfma_f32_16x16x32_bf16(PA2, WF[1][2], ac1, 0, 0, 0); \
        ac1 = __builtin_amdgcn_mfma_f32_16x16x32_bf16(PA3, WF[1][3], ac1, 0, 0, 0); \
        const int c_ = lane & 15, rb_ = (lane >> 4) * 4; \
        _Pragma("unroll") \
        for (int r = 0; r < 4; ++r) { \
            axbuf[AB][rb_ + r][jb + c_]      = ac0[r] + biasv[0]; \
            axbuf[AB][rb_ + r][jb + 16 + c_] = ac1[r] + biasv[1]; \
        } } while (0)

    // ---------------- prologue: prime axbuf[0],[1]; xstage[0]<-x(g2); nr<-x(g3) ----------------
    float4 nr0, nr1;
    if (!hw) {
        float4 p0 = *reinterpret_cast<const float4*>(&xb[t_s * II + i0]);
        float4 p1 = *reinterpret_cast<const float4*>(&xb[t_s * II + i0 + 4]);
        STAGE_X(0, p0, p1);                    // x of group 0
    }
    if (tid < HH) hA[0][tid] = 0;              // bf16 zero (permutation-invariant)
    __syncthreads();
    if (!hw) XPROJ(0, 0);                      // axbuf[0] <- ax(group 0)
    __syncthreads();
    if (!hw) {
        float4 p0 = *reinterpret_cast<const float4*>(&xb[(GS + t_s) * II + i0]);
        float4 p1 = *reinterpret_cast<const float4*>(&xb[(GS + t_s) * II + i0 + 4]);
        STAGE_X(0, p0, p1);                    // x of group 1 (reuse buf 0)
    }
    __syncthreads();
    if (!hw) XPROJ(0, 1);                      // axbuf[1] <- ax(group 1)
    __syncthreads();
    if (!hw) {
        float4 p0 = *reinterpret_cast<const float4*>(&xb[(2 * GS + t_s) * II + i0]);
        float4 p1 = *reinterpret_cast<const float4*>(&xb[(2 * GS + t_s) * II + i0 + 4]);
        STAGE_X(0, p0, p1);                    // xstage[0] <- x of group 2 (window g=0 reads it)
        nr0 = *reinterpret_cast<const float4*>(&xb[(size_t)(3 * GS + t_s) * II + i0]);
        nr1 = *reinterpret_cast<const float4*>(&xb[(size_t)(3 * GS + t_s) * II + i0 + 4]);
    }
    __syncthreads();

    // h-wave persistent state
    float axn0 = 0.f, axn1 = 0.f;
    f32x4 d00 = z4, d10 = z4;      // persistent ax-seeded accumulators
    if (hw) {
        axn0 = axbuf[0][0][jb_h + c16];
        axn1 = axbuf[0][0][jb_h + 16 + c16];
        __builtin_amdgcn_s_setprio(1);    // protect the serial chain's MFMAs
    }

    // x-wave out-store pointer: lane c<16 -> col jb+c; lane 16+c -> col jb+16+c
    float* xout = nullptr;
    if (!hw && lane < 32) {
        xout = out + (size_t)b * (TT * HH) + jb + c16 + ((lane & 16) ? 16 : 0);
    }

    // ---------------- main loop ----------------
    for (int g = 0; g < NG; ++g) {
        const int g3  = g % 3;             // h read buffer
        const int g3n = (g + 1) % 3;       // h w==15 prefetch buffer
        const int g3x = (g + 2) % 3;       // x window write buffer
#pragma unroll
        for (int w = 0; w < GS; ++w) {
            if (hw) {
                const int p  = w & 1;
                const int ko = (lane >> 4) * 8;
                // A = h broadcast into all 16 rows (permuted k-layout matches WH)
                const short8 A0 = *reinterpret_cast<const short8*>(&hA[p][ 0 + ko]);
                const short8 A1 = *reinterpret_cast<const short8*>(&hA[p][32 + ko]);
                const short8 A2 = *reinterpret_cast<const short8*>(&hA[p][64 + ko]);
                const short8 A3 = *reinterpret_cast<const short8*>(&hA[p][96 + ko]);
                // seed ax into C of the first acc of each n-tile (1 mov each;
                // stale [1..3] never read, bounded accumulation)
                d00[0] = axn0;
                d10[0] = axn1;
                f32x4 e01, e02, e03, e11, e12, e13;
                d00 = __builtin_amdgcn_mfma_f32_16x16x32_bf16(A0, WH[0][0], d00, 0, 0, 0);
                e01 = __builtin_amdgcn_mfma_f32_16x16x32_bf16(A1, WH[0][1], z4,  0, 0, 0);
                e02 = __builtin_amdgcn_mfma_f32_16x16x32_bf16(A2, WH[0][2], z4,  0, 0, 0);
                e03 = __builtin_amdgcn_mfma_f32_16x16x32_bf16(A3, WH[0][3], z4,  0, 0, 0);
                d10 = __builtin_amdgcn_mfma_f32_16x16x32_bf16(A0, WH[1][0], d10, 0, 0, 0);
                e11 = __builtin_amdgcn_mfma_f32_16x16x32_bf16(A1, WH[1][1], z4,  0, 0, 0);
                e12 = __builtin_amdgcn_mfma_f32_16x16x32_bf16(A2, WH[1][2], z4,  0, 0, 0);
                e13 = __builtin_amdgcn_mfma_f32_16x16x32_bf16(A3, WH[1][3], z4,  0, 0, 0);
                // prefetch next step's ax (hidden under MFMA completion).
                // w==15 reads next group's buffer — written a FULL group ago
                // (distance-2 pipeline), so no race with this group's window.
                {
                    const int wn  = (w + 1) & (GS - 1);
                    const int gnb = (w == GS - 1) ? g3n : g3;
                    axn0 = axbuf[gnb][wn][jb_h + c16];
                    axn1 = axbuf[gnb][wn][jb_h + 16 + c16];
                }
                // 2-level add tree (ax already inside d00/d10)
                const float s0 = (d00[0] + e01[0]) + (e02[0] + e03[0]);
                const float s1 = (d10[0] + e11[0]) + (e12[0] + e13[0]);
                const float hn0 = tanh_fast(s0);
                const float hn1 = tanh_fast(s1);
                const unsigned int hpk = cvtpk(hn0, hn1);
                if (lane < 16) {
                    // permuted layout: cols (jb_h+lane, jb_h+16+lane) are
                    // adjacent slots -> ONE packed dword write
                    *reinterpret_cast<unsigned int*>(&hA[p ^ 1][jb_h + 2 * lane]) = hpk;
                }
            } else {
                // ---- park-and-store: stream out[T-1] from hA while h computes T ----
                const int T = (g << 4) + w;
                if (T != 0 && lane < 32) {
                    const unsigned int rd = *reinterpret_cast<const unsigned int*>(
                        &hA[w & 1][jb + 2 * c16]);
                    const unsigned int v = (lane & 16) ? (rd & 0xffff0000u) : (rd << 16);
                    xout[(size_t)(T - 1) * HH] = __uint_as_float(v);
                }
                if (w == 14) {
                    // ---- the ENTIRE per-group x pipeline, one window ----
                    if (g + 2 < NG) {
                        // project ax for group g+2 from xstage[g&1] (staged at window g-1)
                        const short8 XA0 = *reinterpret_cast<const short8*>(&xstage[g & 1][0][lane][0]);
                        const short8 XA1 = *reinterpret_cast<const short8*>(&xstage[g & 1][1][lane][0]);
                        const short8 XA2 = *reinterpret_cast<const short8*>(&xstage[g & 1][2][lane][0]);
                        const short8 XA3 = *reinterpret_cast<const short8*>(&xstage[g & 1][3][lane][0]);
                        // 8 independent MFMAs (bias-seeded first pair) + 2-level tree
                        f32x4 xp0, xp1, xp2, xp3, yp0, yp1, yp2, yp3;
                        xp0 = __builtin_amdgcn_mfma_f32_16x16x32_bf16(XA0, WF[0][0], bs0, 0, 0, 0);
                        yp0 = __builtin_amdgcn_mfma_f32_16x16x32_bf16(XA0, WF[1][0], bs1, 0, 0, 0);
                        xp1 = __builtin_amdgcn_mfma_f32_16x16x32_bf16(XA1, WF[0][1], z4, 0, 0, 0);
                        yp1 = __builtin_amdgcn_mfma_f32_16x16x32_bf16(XA1, WF[1][1], z4, 0, 0, 0);
                        xp2 = __builtin_amdgcn_mfma_f32_16x16x32_bf16(XA2, WF[0][2], z4, 0, 0, 0);
                        yp2 = __builtin_amdgcn_mfma_f32_16x16x32_bf16(XA2, WF[1][2], z4, 0, 0, 0);
                        xp3 = __builtin_amdgcn_mfma_f32_16x16x32_bf16(XA3, WF[0][3], z4, 0, 0, 0);
                        yp3 = __builtin_amdgcn_mfma_f32_16x16x32_bf16(XA3, WF[1][3], z4, 0, 0, 0);
                        const f32x4 t0 = (xp0 + xp1) + (xp2 + xp3);
                        const f32x4 t1 = (yp0 + yp1) + (yp2 + yp3);
                        const int c_ = lane & 15, rb_ = (lane >> 4) * 4;
#pragma unroll
                        for (int r = 0; r < 4; ++r) {
                            axbuf[g3x][rb_ + r][jb + c_]      = t0[r];
                            axbuf[g3x][rb_ + r][jb + 16 + c_] = t1[r];
                        }
                    }
                    if (g + 3 < NG) {
                        STAGE_X((g + 1) & 1, nr0, nr1);   // x of group g+3 (loaded last window)
                    }
                    if (g + 4 < NG) {
                        const int tb = (g + 4) * GS;      // load x of group g+4 for next window
                        nr0 = *reinterpret_cast<const float4*>(&xb[(size_t)(tb + t_s) * II + i0]);
                        nr1 = *reinterpret_cast<const float4*>(&xb[(size_t)(tb + t_s) * II + i0 + 4]);
                    }
                }
            }
            step_barrier();
        }
    }

    // ---------------- epilogue: flush out[TT-1] (in hA[0] after last step) ----------------
    if (!hw && lane < 32) {
        const unsigned int rd = *reinterpret_cast<const unsigned int*>(
            &hA[0][jb + 2 * c16]);
        const unsigned int v = (lane & 16) ? (rd & 0xffff0000u) : (rd << 16);
        xout[(size_t)(TT - 1) * HH] = __uint_as_float(v);
    }
#undef XPROJ
#undef STAGE_X
}

extern "C" void kernel_launch(void* const* d_in, const int* in_sizes, int n_in,
                              void* d_out, int out_size, void* d_ws, size_t ws_size,
                              hipStream_t stream) {
    const float* x    = (const float*)d_in[0];
    const float* w_ih = (const float*)d_in[1];
    const float* w_hh = (const float*)d_in[2];
    const float* b_ih = (const float*)d_in[3];
    const float* b_hh = (const float*)d_in[4];
    float* out = (float*)d_out;

    rnn_pipe<<<BB, 512, 0, stream>>>(x, w_ih, w_hh, b_ih, b_hh, out);
}